// Round 11
// baseline (91.148 us; speedup 1.0000x reference)
//
#include <hip/hip_runtime.h>
#include <cmath>
#include <complex>

// ChebyDecimate: 8th-order Chebyshev-I lowpass (4 cascaded biquads, DF2T,
// zero init state) + decimate-by-2.  x: [32, 131072] f32 -> out: [32, 65536] f32.
//
// v6: overlap-save (H=128), NO LDS, NO barriers. Each thread streams its 48
// contiguous float4 window units directly from global through an 8-deep
// register ring (load m+8 in flight while computing unit m) -> HBM stream
// overlaps compute continuously instead of sitting behind a block barrier
// (v3/v5 lesson: kernel time was phase-serialized memory, not VALU issue).
// Sections software-pipelined + packed 2-wide (v_pk_fma_f32); outputs stored
// directly (thread owns 32 contiguous floats). DAG identical to v3/v5.
// Diagnostic (r9): kernel ~11.8us, harness fixed ~59.7us.

#define T_LEN   131072
#define B_ROWS  32
#define OUT_LEN (T_LEN / 2)
#define L_CHUNK 64
#define H_WARM  128
#define TPB     256
#define CPR     (T_LEN / L_CHUNK)          /* 2048 chunks per row */
#define NBLOCKS (B_ROWS * CPR / TPB)       /* 256 */
#define WUNITS  ((H_WARM + L_CHUNK) / 4)   /* 48 float4 units per thread */
#define DEPTH   8                          /* prefetch ring depth */

typedef float v2f __attribute__((ext_vector_type(2)));

#if defined(__has_builtin)
# if __has_builtin(__builtin_elementwise_fma)
#  define FMA2(a, b, c) __builtin_elementwise_fma((a), (b), (c))
# endif
#endif
#ifndef FMA2
static __device__ __forceinline__ v2f fma2_(v2f a, v2f b, v2f c) {
    v2f r; r.x = fmaf(a.x, b.x, c.x); r.y = fmaf(a.y, b.y, c.y); return r;
}
# define FMA2 fma2_
#endif

struct Coef { float g; float a1[4]; float a2[4]; };

__global__ __launch_bounds__(256) void cheby_decimate_kernel(
    const float* __restrict__ x, float* __restrict__ out, Coef c)
{
    const int tid   = blockIdx.x * TPB + threadIdx.x;
    const int row   = tid >> 11;               // / CPR
    const int chunk = tid & (CPR - 1);
    const float4* __restrict__ xu =
        reinterpret_cast<const float4*>(x + (size_t)row * T_LEN);
    const int u0 = 16 * chunk - H_WARM / 4;    // first window unit (may be <0)

    // packed coefficients: pair A = sections (1,3), pair B = sections (2,4)
    const v2f gg   = { c.g, c.g };
    const v2f two  = { 2.f, 2.f };
    const v2f naA1 = { -c.a1[0], -c.a1[2] }, naA2 = { -c.a2[0], -c.a2[2] };
    const v2f naB1 = { -c.a1[1], -c.a1[3] }, naB2 = { -c.a2[1], -c.a2[3] };

    v2f zA1 = {0.f,0.f}, zA2 = {0.f,0.f}, zB1 = {0.f,0.f}, zB2 = {0.f,0.f};
    v2f o13 = {0.f,0.f}, o24 = {0.f,0.f};   // previous-step pair outputs

    const float4 zf4 = make_float4(0.f, 0.f, 0.f, 0.f);

    // ---- prime the prefetch ring (units 0..DEPTH-1) ----
    float4 ring[DEPTH];
    #pragma unroll
    for (int k = 0; k < DEPTH; ++k) {
        int g = u0 + k;
        ring[k] = (g >= 0) ? xu[g] : zf4;      // g<0: zero initial state
    }

    // one pipelined, packed step; o24.y = section-4 output of sample i-3
#define PSTEP(xi, STORE) do {                                                  \
        v2f i13; i13.x = (xi); i13.y = o24.x;                                  \
        v2f i24 = o13;                                                         \
        v2f wA = gg * i13; v2f oA = wA + zA1; v2f tA = FMA2(two, wA, zA2);     \
        zA1 = FMA2(naA1, oA, tA); zA2 = FMA2(naA2, oA, wA);                    \
        v2f wB = gg * i24; v2f oB = wB + zB1; v2f tB = FMA2(two, wB, zB2);     \
        zB1 = FMA2(naB1, oB, tB); zB2 = FMA2(naB2, oB, wB);                    \
        o13 = oA; o24 = oB; STORE;                                             \
    } while (0)

    float outv[32];

    // warm-up: units m=0..31 (samples 0..127; none live). Refill ring at m+8.
    #pragma unroll 8
    for (int m = 0; m < 32; ++m) {
        float4 cur = ring[m & (DEPTH - 1)];
        int g = u0 + m + DEPTH;                // <= u0+39 < window end always
        ring[m & (DEPTH - 1)] = (g >= 0) ? xu[g] : zf4;
        PSTEP(cur.x, (void)0); PSTEP(cur.y, (void)0);
        PSTEP(cur.z, (void)0); PSTEP(cur.w, (void)0);
    }
    // live: m=32..48; store o24.y (sample 4m-2 at sub-step 1, 4m at sub-step 3)
    #pragma unroll
    for (int m = 32; m <= 48; ++m) {
        float4 cur = ring[m & (DEPTH - 1)];
        ring[m & (DEPTH - 1)] = (m + DEPTH < WUNITS) ? xu[u0 + m + DEPTH] : zf4;
        PSTEP(cur.x, (void)0);
        PSTEP(cur.y, if (m >= 33) outv[2*m - 65] = o24.y);
        PSTEP(cur.z, (void)0);
        PSTEP(cur.w, if (m <= 47) outv[2*m - 64] = o24.y);
    }
#undef PSTEP

    // ---- direct stores: thread owns 32 contiguous output floats ----
    float* __restrict__ op = out + (size_t)row * OUT_LEN + 32 * (size_t)chunk;
    #pragma unroll
    for (int q = 0; q < 8; ++q) {
        *reinterpret_cast<float4*>(op + 4 * q) =
            make_float4(outv[4*q], outv[4*q+1], outv[4*q+2], outv[4*q+3]);
    }
}

extern "C" void kernel_launch(void* const* d_in, const int* in_sizes, int n_in,
                              void* d_out, int out_size, void* d_ws, size_t ws_size,
                              hipStream_t stream)
{
    const float* x = (const float*)d_in[0];
    float* out = (float*)d_out;

    // cheby1(N=8, rp=0.05dB, Wn=0.5) SOS design in f64, exactly mirroring the
    // reference's math, then cast to f32 like jnp.asarray(..., float32).
    const int N = 8;
    const double rp = 0.05;
    const double eps = std::sqrt(std::pow(10.0, rp / 10.0) - 1.0);
    const double mu  = std::asinh(1.0 / eps) / N;

    std::complex<double> p[8];
    std::complex<double> prodnp(1.0, 0.0);
    for (int i = 0; i < N; ++i) {
        double theta = M_PI * (2.0 * (i + 1) - 1.0) / (2.0 * N);
        p[i] = std::complex<double>(-std::sinh(mu) * std::sin(theta),
                                     std::cosh(mu) * std::cos(theta));
        prodnp *= -p[i];
    }
    double gain = prodnp.real() / std::sqrt(1.0 + eps * eps);  // N even

    const double fs = 2.0;
    const double warped = 2.0 * fs * std::tan(M_PI * 0.5 / fs);  // = 4
    std::complex<double> prodden(1.0, 0.0);
    std::complex<double> pz[8];
    for (int i = 0; i < N; ++i) {
        p[i] *= warped;
        pz[i] = (2.0 * fs + p[i]) / (2.0 * fs - p[i]);
        prodden *= (2.0 * fs - p[i]);
    }
    gain *= std::pow(warped, (double)N);
    gain /= prodden.real();

    Coef c;
    int ns = 0;
    double A1[4], A2[4];
    for (int i = 0; i < N; ++i) {
        if (pz[i].imag() > 0.0) {
            A1[ns] = -2.0 * pz[i].real();
            A2[ns] = std::norm(pz[i]);
            ++ns;
        }
    }
    const double gsec = std::pow(gain, 1.0 / ns);
    c.g = (float)gsec;
    for (int s = 0; s < 4; ++s) { c.a1[s] = (float)A1[s]; c.a2[s] = (float)A2[s]; }

    dim3 block(TPB), grid(NBLOCKS);
    hipLaunchKernelGGL(cheby_decimate_kernel, grid, block, 0, stream, x, out, c);
}

// Round 13
// 71.853 us; speedup vs baseline: 1.2685x; 1.2685x over previous
//
#include <hip/hip_runtime.h>
#include <cmath>
#include <complex>

// ChebyDecimate: 8th-order Chebyshev-I lowpass (4 cascaded biquads, DF2T,
// zero init state) + decimate-by-2.  x: [32, 131072] f32 -> out: [32, 65536] f32.
//
// v7: overlap-save with LDS staging (v6 lesson: direct global streaming
// overfetches 3.6x -> LDS dedup is essential), restructured for PHASE OVERLAP:
// 512 blocks x 256 thr, L=32 live/thread, H=96 warm-up, 33KB LDS -> 2 blocks
// resident per CU, so one block's compute overlaps the other's staging barrier
// (v5 lesson: the 11.8us kernel was phase-serialized, not issue-bound).
// Sections software-pipelined + packed 2-wide (v_pk_fma_f32); direct stores.
// Diagnostic (r9): harness fixed floor ~59.7us; v5 kernel ~11.8us.

#define T_LEN   131072
#define B_ROWS  32
#define OUT_LEN (T_LEN / 2)
#define L_CHUNK 32
#define H_WARM  96
#define TPB     256
#define LIVE_PER_BLOCK (TPB * L_CHUNK)               /* 8192 */
#define BLOCKS_PER_ROW (T_LEN / LIVE_PER_BLOCK)      /* 16 */
#define NBLOCKS (B_ROWS * BLOCKS_PER_ROW)            /* 512 */
#define WIN_FLOATS (LIVE_PER_BLOCK + H_WARM)         /* 8288 */
#define WIN_UNITS  (WIN_FLOATS / 4)                  /* 2072 float4s = 33.2KB */

typedef float v2f __attribute__((ext_vector_type(2)));

#if defined(__has_builtin)
# if __has_builtin(__builtin_elementwise_fma)
#  define FMA2(a, b, c) __builtin_elementwise_fma((a), (b), (c))
# endif
#endif
#ifndef FMA2
static __device__ __forceinline__ v2f fma2_(v2f a, v2f b, v2f c) {
    v2f r; r.x = fmaf(a.x, b.x, c.x); r.y = fmaf(a.y, b.y, c.y); return r;
}
# define FMA2 fma2_
#endif

struct Coef { float g; float a1[4]; float a2[4]; };

__global__ __launch_bounds__(TPB, 2) void cheby_decimate_kernel(
    const float* __restrict__ x, float* __restrict__ out, Coef c)
{
    __shared__ float4 lds[WIN_UNITS];
    const int t   = threadIdx.x;
    const int row = blockIdx.x / BLOCKS_PER_ROW;
    const int bc  = blockIdx.x % BLOCKS_PER_ROW;
    const float* __restrict__ xr = x + (size_t)row * T_LEN;
    const int wstart = bc * LIVE_PER_BLOCK - H_WARM;    // first float of window

    // swizzle on 16B units within 8-unit (128B) groups: u' = u ^ ((u>>3)&7)
    // write side: consecutive lanes write consecutive units -> conflict-free;
    // read side: lane stride 8 units -> slot varies with (t&7) -> even spread.
#define SWZ(u) ((u) ^ (((u) >> 3) & 7))

    // ---- coalesced global -> LDS staging ----
    #pragma unroll
    for (int k = 0; k < (WIN_UNITS + TPB - 1) / TPB; ++k) {
        int w = t + TPB * k;
        if (w < WIN_UNITS) {
            int g = wstart + 4 * w;                     // aligned, mult of 4
            float4 v = make_float4(0.f, 0.f, 0.f, 0.f); // g<0: zero init state
            if (g >= 0) v = *reinterpret_cast<const float4*>(xr + g);
            lds[SWZ(w)] = v;
        }
    }
    __syncthreads();

    // packed coefficients: pair A = sections (1,3), pair B = sections (2,4)
    const v2f gg   = { c.g, c.g };
    const v2f two  = { 2.f, 2.f };
    const v2f naA1 = { -c.a1[0], -c.a1[2] }, naA2 = { -c.a2[0], -c.a2[2] };
    const v2f naB1 = { -c.a1[1], -c.a1[3] }, naB2 = { -c.a2[1], -c.a2[3] };

    v2f zA1 = {0.f,0.f}, zA2 = {0.f,0.f}, zB1 = {0.f,0.f}, zB2 = {0.f,0.f};
    v2f o13 = {0.f,0.f}, o24 = {0.f,0.f};   // previous-step pair outputs

#define LREAD(u) lds[SWZ(u)]
    // one pipelined, packed step; o24.y = section-4 output of sample i-3
#define PSTEP(xi, STORE) do {                                                  \
        v2f i13; i13.x = (xi); i13.y = o24.x;                                  \
        v2f i24 = o13;                                                         \
        v2f wA = gg * i13; v2f oA = wA + zA1; v2f tA = FMA2(two, wA, zA2);     \
        zA1 = FMA2(naA1, oA, tA); zA2 = FMA2(naA2, oA, wA);                    \
        v2f wB = gg * i24; v2f oB = wB + zB1; v2f tB = FMA2(two, wB, zB2);     \
        zB1 = FMA2(naB1, oB, tB); zB2 = FMA2(naB2, oB, wB);                    \
        o13 = oA; o24 = oB; STORE;                                             \
    } while (0)

    // thread t: window units [8t, 8t+32) = 128 samples (96 warm + 32 live)
    const int ub = 8 * t;
    float4 cur = LREAD(ub);
    float outv[16];

    // warm-up: groups m=0..23 (samples 0..95 consumed; none live)
    #pragma unroll 4
    for (int m = 0; m < 24; ++m) {
        float4 nxt = LREAD(ub + m + 1);
        PSTEP(cur.x, (void)0); PSTEP(cur.y, (void)0);
        PSTEP(cur.z, (void)0); PSTEP(cur.w, (void)0);
        cur = nxt;
    }
    // live: groups m=24..32 (m=32 = zero-fed flush); o24.y at sub-step 1 is
    // sample 4m-2, at sub-step 3 sample 4m; keep even samples 96..126.
    #pragma unroll
    for (int m = 24; m <= 32; ++m) {
        float4 nxt = (m < 31) ? LREAD(ub + m + 1)
                              : make_float4(0.f, 0.f, 0.f, 0.f);
        PSTEP(cur.x, (void)0);
        PSTEP(cur.y, if (m >= 25) outv[2*m - 49] = o24.y);
        PSTEP(cur.z, (void)0);
        PSTEP(cur.w, if (m <= 31) outv[2*m - 48] = o24.y);
        cur = nxt;
    }
#undef PSTEP
#undef LREAD
#undef SWZ

    // ---- direct stores: thread owns 16 contiguous floats = one 64B line ----
    float* __restrict__ op = out + (size_t)row * OUT_LEN
                                 + (size_t)bc * (LIVE_PER_BLOCK / 2) + 16 * t;
    #pragma unroll
    for (int q = 0; q < 4; ++q) {
        *reinterpret_cast<float4*>(op + 4 * q) =
            make_float4(outv[4*q], outv[4*q+1], outv[4*q+2], outv[4*q+3]);
    }
}

extern "C" void kernel_launch(void* const* d_in, const int* in_sizes, int n_in,
                              void* d_out, int out_size, void* d_ws, size_t ws_size,
                              hipStream_t stream)
{
    const float* x = (const float*)d_in[0];
    float* out = (float*)d_out;

    // cheby1(N=8, rp=0.05dB, Wn=0.5) SOS design in f64, exactly mirroring the
    // reference's math, then cast to f32 like jnp.asarray(..., float32).
    const int N = 8;
    const double rp = 0.05;
    const double eps = std::sqrt(std::pow(10.0, rp / 10.0) - 1.0);
    const double mu  = std::asinh(1.0 / eps) / N;

    std::complex<double> p[8];
    std::complex<double> prodnp(1.0, 0.0);
    for (int i = 0; i < N; ++i) {
        double theta = M_PI * (2.0 * (i + 1) - 1.0) / (2.0 * N);
        p[i] = std::complex<double>(-std::sinh(mu) * std::sin(theta),
                                     std::cosh(mu) * std::cos(theta));
        prodnp *= -p[i];
    }
    double gain = prodnp.real() / std::sqrt(1.0 + eps * eps);  // N even

    const double fs = 2.0;
    const double warped = 2.0 * fs * std::tan(M_PI * 0.5 / fs);  // = 4
    std::complex<double> prodden(1.0, 0.0);
    std::complex<double> pz[8];
    for (int i = 0; i < N; ++i) {
        p[i] *= warped;
        pz[i] = (2.0 * fs + p[i]) / (2.0 * fs - p[i]);
        prodden *= (2.0 * fs - p[i]);
    }
    gain *= std::pow(warped, (double)N);
    gain /= prodden.real();

    Coef c;
    int ns = 0;
    double A1[4], A2[4];
    for (int i = 0; i < N; ++i) {
        if (pz[i].imag() > 0.0) {
            A1[ns] = -2.0 * pz[i].real();
            A2[ns] = std::norm(pz[i]);
            ++ns;
        }
    }
    const double gsec = std::pow(gain, 1.0 / ns);
    c.g = (float)gsec;
    for (int s = 0; s < 4; ++s) { c.a1[s] = (float)A1[s]; c.a2[s] = (float)A2[s]; }

    dim3 block(TPB), grid(NBLOCKS);
    hipLaunchKernelGGL(cheby_decimate_kernel, grid, block, 0, stream, x, out, c);
}